// Round 1
// baseline (650.626 us; speedup 1.0000x reference)
//
#include <hip/hip_runtime.h>

// Neural Additive Model: 256 per-feature MLPs 1->128->64->32->1 (ReLU), summed.
// B=8192. All fp32. Compute-bound: 43.6 GFLOP, ~18.5 MB traffic.
// Round 1: fp32 vector baseline. One block = (1 feature, 256 batch elems),
// 1 batch elem / thread. Weight indices are wave-uniform -> compiler should
// emit s_load + v_fmac_f32(v,s,v): 1 VALU instr per MAC.

#define NF   256
#define NH1  128
#define NH2  64
#define NH3  32
#define NB   8192

__global__ __launch_bounds__(256) void init_out_kernel(float* __restrict__ out,
                                                       const float* __restrict__ bias) {
    int i = blockIdx.x * 256 + threadIdx.x;
    if (i < NB) out[i] = bias[0];
}

__global__ __launch_bounds__(256) void nam_kernel(
    const float* __restrict__ x,
    const float* __restrict__ W1, const float* __restrict__ b1,
    const float* __restrict__ W2, const float* __restrict__ b2,
    const float* __restrict__ W3, const float* __restrict__ b3,
    const float* __restrict__ W4, const float* __restrict__ b4,
    float* __restrict__ out)
{
    const int f  = blockIdx.x & (NF - 1);   // feature (uniform per block)
    const int bt = blockIdx.x >> 8;         // batch tile
    const int b  = bt * 256 + threadIdx.x;  // batch element (per lane)

    const float xv = x[b * NF + f];         // strided, but one load/thread total

    const float* __restrict__ w1  = W1 + f * NH1;
    const float* __restrict__ bb1 = b1 + f * NH1;
    const float* __restrict__ w2  = W2 + f * NH1 * NH2;
    const float* __restrict__ bb2 = b2 + f * NH2;
    const float* __restrict__ w3  = W3 + f * NH2 * NH3;
    const float* __restrict__ bb3 = b3 + f * NH3;
    const float* __restrict__ w4  = W4 + f * NH3;

    // ---- layer 1 + 2 fused: h2[k] = sum_j relu(x*W1[j]+b1[j]) * W2[j][k] ----
    float h2[NH2];
    #pragma unroll
    for (int k = 0; k < NH2; ++k) h2[k] = bb2[k];

    #pragma unroll 2
    for (int j = 0; j < NH1; ++j) {
        const float h1 = fmaxf(fmaf(xv, w1[j], bb1[j]), 0.0f);
        const float* __restrict__ w2row = w2 + j * NH2;
        #pragma unroll
        for (int k = 0; k < NH2; ++k) h2[k] = fmaf(h1, w2row[k], h2[k]);
    }
    #pragma unroll
    for (int k = 0; k < NH2; ++k) h2[k] = fmaxf(h2[k], 0.0f);

    // ---- layer 3: h3[m] = relu(sum_k h2[k] * W3[k][m] + b3[m]) ----
    float h3[NH3];
    #pragma unroll
    for (int m = 0; m < NH3; ++m) h3[m] = bb3[m];

    #pragma unroll 2
    for (int k = 0; k < NH2; ++k) {
        const float* __restrict__ w3row = w3 + k * NH3;
        #pragma unroll
        for (int m = 0; m < NH3; ++m) h3[m] = fmaf(h2[k], w3row[m], h3[m]);
    }

    // ---- layer 4: o = sum_m relu(h3[m]) * W4[m] + b4 ----
    float o = b4[f];
    #pragma unroll
    for (int m = 0; m < NH3; ++m) o = fmaf(fmaxf(h3[m], 0.0f), w4[m], o);

    // ---- sum over features ----
    atomicAdd(&out[b], o);
}

extern "C" void kernel_launch(void* const* d_in, const int* in_sizes, int n_in,
                              void* d_out, int out_size, void* d_ws, size_t ws_size,
                              hipStream_t stream) {
    const float* x    = (const float*)d_in[0];
    const float* W1   = (const float*)d_in[1];
    const float* b1   = (const float*)d_in[2];
    const float* W2   = (const float*)d_in[3];
    const float* b2   = (const float*)d_in[4];
    const float* W3   = (const float*)d_in[5];
    const float* b3   = (const float*)d_in[6];
    const float* W4   = (const float*)d_in[7];
    const float* b4   = (const float*)d_in[8];
    const float* bias = (const float*)d_in[9];
    float* out = (float*)d_out;

    // d_out is poisoned (0xAA) before every launch: initialize to bias.
    init_out_kernel<<<NB / 256, 256, 0, stream>>>(out, bias);

    // 256 features x 32 batch tiles
    nam_kernel<<<NF * (NB / 256), 256, 0, stream>>>(
        x, W1, b1, W2, b2, W3, b3, W4, b4, out);
}